// Round 5
// baseline (3161.881 us; speedup 1.0000x reference)
//
#include <hip/hip_runtime.h>
#include <hip/hip_bf16.h>

typedef unsigned short u16;
typedef unsigned int u32;
typedef short s16x8 __attribute__((ext_vector_type(8)));
typedef float f32x4 __attribute__((ext_vector_type(4)));
typedef float f32x2 __attribute__((ext_vector_type(2)));

__device__ __forceinline__ float bf2f(u16 u) {
    union { u32 i; float f; } v; v.i = ((u32)u) << 16; return v.f;
}
__device__ __forceinline__ u16 f2bf(float f) {
    union { float f; u32 i; } v; v.f = f;
    u32 i = v.i;
    u32 r = (i + 0x7FFFu + ((i >> 16) & 1u)) >> 16;   // round-to-nearest-even
    return (u16)r;
}

// ---------------------------------------------------------------------------
// Convert f32 -> bf16, 2 elements/thread. n must be even.
// ---------------------------------------------------------------------------
__global__ __launch_bounds__(256) void cvt_f32_bf16(
    const float* __restrict__ in, u16* __restrict__ out, long long n2)
{
    long long i = (long long)blockIdx.x * 256 + threadIdx.x;
    if (i < n2) {
        f32x2 v = *(const f32x2*)(in + i * 2);
        u32 p = (u32)f2bf(v[0]) | ((u32)f2bf(v[1]) << 16);
        *(u32*)(out + i * 2) = p;
    }
}

// ---------------------------------------------------------------------------
// Transpose + convert: f32 in[R][C] -> bf16 out[C][R].  R,C multiples of 32.
// ---------------------------------------------------------------------------
__global__ __launch_bounds__(256) void transpose_f32_bf16(
    const float* __restrict__ in, u16* __restrict__ out, int R, int C)
{
    __shared__ u16 t[32][33];
    int tx = threadIdx.x & 31, ty = threadIdx.x >> 5;   // ty 0..7
    int c0 = blockIdx.x * 32, r0 = blockIdx.y * 32;
    #pragma unroll
    for (int i = 0; i < 32; i += 8)
        t[ty + i][tx] = f2bf(in[(size_t)(r0 + ty + i) * C + c0 + tx]);
    __syncthreads();
    #pragma unroll
    for (int i = 0; i < 32; i += 8)
        out[(size_t)(c0 + ty + i) * R + r0 + tx] = t[tx][ty + i];
}

// ---------------------------------------------------------------------------
// GEMM: C[M][N] = A[M][K] * Bt[N][K]^T   (A,Bt bf16, C bf16, f32 accumulate)
// 64x64 tile, 256 threads = 4 waves (2x2 of 32x32 per wave), K-chunk 32.
// ---------------------------------------------------------------------------
__global__ __launch_bounds__(256) void gemm_bf16(
    const u16* __restrict__ A, const u16* __restrict__ Bt, u16* __restrict__ C,
    int M, int N, int K)
{
    __shared__ u16 As[64][40];
    __shared__ u16 Bs[64][40];

    const int tid  = threadIdx.x;
    const int wave = tid >> 6, lane = tid & 63;
    const int quad = lane >> 4, l16 = lane & 15;
    const int m0 = blockIdx.y * 64, n0 = blockIdx.x * 64;
    const int wm = (wave >> 1) * 32, wn = (wave & 1) * 32;

    const int srow = tid >> 2;            // 0..63
    const int koff = (tid & 3) * 8;       // 0,8,16,24

    f32x4 acc00 = {0.f,0.f,0.f,0.f};
    f32x4 acc01 = {0.f,0.f,0.f,0.f};
    f32x4 acc10 = {0.f,0.f,0.f,0.f};
    f32x4 acc11 = {0.f,0.f,0.f,0.f};

    for (int k0 = 0; k0 < K; k0 += 32) {
        *(s16x8*)&As[srow][koff] = *(const s16x8*)&A[(size_t)(m0 + srow) * K + k0 + koff];
        *(s16x8*)&Bs[srow][koff] = *(const s16x8*)&Bt[(size_t)(n0 + srow) * K + k0 + koff];
        __syncthreads();
        s16x8 a0 = *(const s16x8*)&As[wm + l16][quad * 8];
        s16x8 a1 = *(const s16x8*)&As[wm + 16 + l16][quad * 8];
        s16x8 b0 = *(const s16x8*)&Bs[wn + l16][quad * 8];
        s16x8 b1 = *(const s16x8*)&Bs[wn + 16 + l16][quad * 8];
        acc00 = __builtin_amdgcn_mfma_f32_16x16x32_bf16(a0, b0, acc00, 0, 0, 0);
        acc01 = __builtin_amdgcn_mfma_f32_16x16x32_bf16(a0, b1, acc01, 0, 0, 0);
        acc10 = __builtin_amdgcn_mfma_f32_16x16x32_bf16(a1, b0, acc10, 0, 0, 0);
        acc11 = __builtin_amdgcn_mfma_f32_16x16x32_bf16(a1, b1, acc11, 0, 0, 0);
        __syncthreads();
    }

    #pragma unroll
    for (int r = 0; r < 4; ++r) {
        int row0 = m0 + wm + quad * 4 + r;
        int col0 = n0 + wn + l16;
        C[(size_t)row0 * N + col0]             = f2bf(acc00[r]);
        C[(size_t)row0 * N + col0 + 16]        = f2bf(acc01[r]);
        C[(size_t)(row0 + 16) * N + col0]      = f2bf(acc10[r]);
        C[(size_t)(row0 + 16) * N + col0 + 16] = f2bf(acc11[r]);
    }
}

// ---------------------------------------------------------------------------
// Same GEMM but with FLOAT32 output (for the final o-projection: the
// reference's output dtype is f32, so d_out is float*).
// ---------------------------------------------------------------------------
__global__ __launch_bounds__(256) void gemm_bf16_f32out(
    const u16* __restrict__ A, const u16* __restrict__ Bt, float* __restrict__ C,
    int M, int N, int K)
{
    __shared__ u16 As[64][40];
    __shared__ u16 Bs[64][40];

    const int tid  = threadIdx.x;
    const int wave = tid >> 6, lane = tid & 63;
    const int quad = lane >> 4, l16 = lane & 15;
    const int m0 = blockIdx.y * 64, n0 = blockIdx.x * 64;
    const int wm = (wave >> 1) * 32, wn = (wave & 1) * 32;

    const int srow = tid >> 2;
    const int koff = (tid & 3) * 8;

    f32x4 acc00 = {0.f,0.f,0.f,0.f};
    f32x4 acc01 = {0.f,0.f,0.f,0.f};
    f32x4 acc10 = {0.f,0.f,0.f,0.f};
    f32x4 acc11 = {0.f,0.f,0.f,0.f};

    for (int k0 = 0; k0 < K; k0 += 32) {
        *(s16x8*)&As[srow][koff] = *(const s16x8*)&A[(size_t)(m0 + srow) * K + k0 + koff];
        *(s16x8*)&Bs[srow][koff] = *(const s16x8*)&Bt[(size_t)(n0 + srow) * K + k0 + koff];
        __syncthreads();
        s16x8 a0 = *(const s16x8*)&As[wm + l16][quad * 8];
        s16x8 a1 = *(const s16x8*)&As[wm + 16 + l16][quad * 8];
        s16x8 b0 = *(const s16x8*)&Bs[wn + l16][quad * 8];
        s16x8 b1 = *(const s16x8*)&Bs[wn + 16 + l16][quad * 8];
        acc00 = __builtin_amdgcn_mfma_f32_16x16x32_bf16(a0, b0, acc00, 0, 0, 0);
        acc01 = __builtin_amdgcn_mfma_f32_16x16x32_bf16(a0, b1, acc01, 0, 0, 0);
        acc10 = __builtin_amdgcn_mfma_f32_16x16x32_bf16(a1, b0, acc10, 0, 0, 0);
        acc11 = __builtin_amdgcn_mfma_f32_16x16x32_bf16(a1, b1, acc11, 0, 0, 0);
        __syncthreads();
    }

    #pragma unroll
    for (int r = 0; r < 4; ++r) {
        int row0 = m0 + wm + quad * 4 + r;
        int col0 = n0 + wn + l16;
        C[(size_t)row0 * N + col0]             = acc00[r];
        C[(size_t)row0 * N + col0 + 16]        = acc01[r];
        C[(size_t)(row0 + 16) * N + col0]      = acc10[r];
        C[(size_t)(row0 + 16) * N + col0 + 16] = acc11[r];
    }
}

// ---------------------------------------------------------------------------
// RMSNorm rows: out = x * rsqrt(mean(x^2)+eps) * w  (x bf16, w f32, out bf16)
// ---------------------------------------------------------------------------
__global__ __launch_bounds__(256) void rmsnorm_kernel(
    const u16* __restrict__ in, const float* __restrict__ w, u16* __restrict__ out,
    int len, int istride, int ostride)
{
    const int row = blockIdx.x, tid = threadIdx.x;
    const u16* x = in + (size_t)row * istride;
    float ss = 0.f;
    for (int i = tid; i < len; i += 256) { float v = bf2f(x[i]); ss += v * v; }
    #pragma unroll
    for (int off = 32; off >= 1; off >>= 1) ss += __shfl_xor(ss, off, 64);
    __shared__ float wsum[4];
    if ((tid & 63) == 0) wsum[tid >> 6] = ss;
    __syncthreads();
    float tot = wsum[0] + wsum[1] + wsum[2] + wsum[3];
    float inv = 1.0f / sqrtf(tot / (float)len + 1e-6f);
    for (int i = tid; i < len; i += 256) {
        float v = bf2f(x[i]);
        out[(size_t)row * ostride + i] = f2bf(v * inv * w[i]);
    }
}

// ---------------------------------------------------------------------------
// RoPE: q rope halves (16 heads, in-place) + k_rope -> krot. cos/sin f32.
// ---------------------------------------------------------------------------
__global__ __launch_bounds__(256) void rope_kernel(
    u16* __restrict__ qb, const u16* __restrict__ kvb, u16* __restrict__ krot,
    const float* __restrict__ cosb, const float* __restrict__ sinb)
{
    const int row = blockIdx.x;
    const int s = row & 2047;
    const int lane = threadIdx.x & 63, wave = threadIdx.x >> 6;
    const float c  = cosb[s * 64 + lane];
    const float sn = sinb[s * 64 + lane];
    for (int seg = wave; seg < 17; seg += 4) {
        const u16* pin; u16* pout;
        if (seg < 16) { pout = qb + (size_t)row * 3072 + seg * 192 + 128; pin = pout; }
        else          { pin = kvb + (size_t)row * 576 + 512; pout = krot + (size_t)row * 64; }
        float x  = bf2f(pin[lane]);
        float xp = bf2f(pin[lane ^ 32]);
        float rot = (lane < 32) ? -xp : xp;
        pout[lane] = f2bf(x * c + rot * sn);
    }
}

// ---------------------------------------------------------------------------
// Flash attention (f32 VALU, online softmax).
// Block: 256 thr, TQ=32 q-rows of one (b,h); loop over TK=32 key chunks.
// grid = (S/32, NH, B)
// ---------------------------------------------------------------------------
#define ATQ 32
#define ATK 32
__global__ __launch_bounds__(256) void attn_kernel(
    const u16* __restrict__ qb,     // [4096][3072]  (rope applied)
    const u16* __restrict__ kvup,   // [4096][4096]  (per head: 128 nope | 128 v)
    const u16* __restrict__ krot,   // [4096][64]
    const float* __restrict__ mask, // [2][2048]
    u16* __restrict__ attnb)        // [4096][2048]
{
    __shared__ float Qs[ATQ][196];
    __shared__ float Ks[ATK][196];
    __shared__ float Sb[ATQ][33];
    __shared__ float mrow[ATQ], lrow[ATQ], mnew[ATQ], arow[ATQ];

    const int tid = threadIdx.x;
    const int qt = blockIdx.x, h = blockIdx.y, b = blockIdx.z;
    const int row0 = b * 2048 + qt * ATQ;

    const float scale = 0.07216878364870323f;   // 1/sqrt(192)
    for (int idx = tid; idx < ATQ * 192; idx += 256) {
        int r = idx / 192, c = idx - r * 192;
        Qs[r][c] = bf2f(qb[(size_t)(row0 + r) * 3072 + h * 192 + c]) * scale;
    }
    if (tid < ATQ) { mrow[tid] = -__builtin_inff(); lrow[tid] = 0.f; }

    float acc[8][2];
    #pragma unroll
    for (int j = 0; j < 8; ++j) { acc[j][0] = 0.f; acc[j][1] = 0.f; }

    const int kslot = tid & 31, qs = tid >> 5;    // score mapping
    const int dd = (tid & 63) * 2, qh = tid >> 6; // PV mapping

    for (int kc = 0; kc < 2048 / ATK; ++kc) {
        const int krow0 = b * 2048 + kc * ATK;
        __syncthreads();
        for (int idx = tid; idx < ATK * 192; idx += 256) {
            int r = idx / 192, c = idx - r * 192;
            float v;
            if (c < 128) v = bf2f(kvup[(size_t)(krow0 + r) * 4096 + h * 256 + c]);
            else         v = bf2f(krot[(size_t)(krow0 + r) * 64 + (c - 128)]);
            Ks[r][c] = v;
        }
        __syncthreads();
        {
            float d0 = 0.f, d1 = 0.f, d2 = 0.f, d3 = 0.f;
            for (int c = 0; c < 192; c += 4) {
                const f32x4 kk = *(const f32x4*)&Ks[kslot][c];
                const f32x4 q0 = *(const f32x4*)&Qs[qs][c];
                const f32x4 q1 = *(const f32x4*)&Qs[qs + 8][c];
                const f32x4 q2 = *(const f32x4*)&Qs[qs + 16][c];
                const f32x4 q3 = *(const f32x4*)&Qs[qs + 24][c];
                #pragma unroll
                for (int t = 0; t < 4; ++t) {
                    d0 += q0[t] * kk[t]; d1 += q1[t] * kk[t];
                    d2 += q2[t] * kk[t]; d3 += q3[t] * kk[t];
                }
            }
            float mval = mask[b * 2048 + kc * ATK + kslot];
            Sb[qs][kslot]      = d0 + mval;
            Sb[qs + 8][kslot]  = d1 + mval;
            Sb[qs + 16][kslot] = d2 + mval;
            Sb[qs + 24][kslot] = d3 + mval;
        }
        __syncthreads();
        if (tid < ATQ) {
            float mr = -__builtin_inff();
            #pragma unroll
            for (int k = 0; k < ATK; ++k) mr = fmaxf(mr, Sb[tid][k]);
            float mn = fmaxf(mrow[tid], mr);
            mnew[tid] = mn;
            arow[tid] = __expf(mrow[tid] - mn);
            mrow[tid] = mn;
        }
        __syncthreads();
        #pragma unroll
        for (int i = 0; i < 4; ++i) {
            int idx = tid + i * 256;
            int q_ = idx >> 5, k_ = idx & 31;
            Sb[q_][k_] = __expf(Sb[q_][k_] - mnew[q_]);
        }
        __syncthreads();
        if (tid < ATQ) {
            float sum = 0.f;
            #pragma unroll
            for (int k = 0; k < ATK; ++k) sum += Sb[tid][k];
            lrow[tid] = lrow[tid] * arow[tid] + sum;
        }
        {
            #pragma unroll
            for (int j = 0; j < 8; ++j) {
                float a = arow[qh * 8 + j];
                acc[j][0] *= a; acc[j][1] *= a;
            }
            const u16* vbase = kvup + (size_t)krow0 * 4096 + h * 256 + 128 + dd;
            for (int k = 0; k < ATK; ++k) {
                u32 vv = *(const u32*)(vbase + (size_t)k * 4096);
                float v0 = bf2f((u16)(vv & 0xffffu));
                float v1 = bf2f((u16)(vv >> 16));
                #pragma unroll
                for (int j = 0; j < 8; ++j) {
                    float p = Sb[qh * 8 + j][k];
                    acc[j][0] += p * v0; acc[j][1] += p * v1;
                }
            }
        }
    }
    __syncthreads();
    #pragma unroll
    for (int j = 0; j < 8; ++j) {
        int q_ = qh * 8 + j;
        float linv = 1.0f / lrow[q_];
        u32 o0 = f2bf(acc[j][0] * linv);
        u32 o1 = f2bf(acc[j][1] * linv);
        *(u32*)&attnb[(size_t)(row0 + q_) * 2048 + h * 128 + dd] = o0 | (o1 << 16);
    }
}

// ---------------------------------------------------------------------------
// Workspace layout (u16 elements) — round-3 lifetime-reuse layout (proven).
// ---------------------------------------------------------------------------
extern "C" void kernel_launch(void* const* d_in, const int* in_sizes, int n_in,
                              void* d_out, int out_size, void* d_ws, size_t ws_size,
                              hipStream_t stream)
{
    // Inputs f32 per the reference; OUTPUT f32 per the reference (d_out = float*).
    const float* hidden = (const float*)d_in[0];
    const float* mask   = (const float*)d_in[1];
    const float* cosb   = (const float*)d_in[2];
    const float* sinb   = (const float*)d_in[3];
    const float* w_qd   = (const float*)d_in[4];
    const float* w_qu   = (const float*)d_in[5];
    const float* w_kvd  = (const float*)d_in[6];
    const float* w_kvu  = (const float*)d_in[7];
    const float* w_o    = (const float*)d_in[8];
    const float* qnw    = (const float*)d_in[9];
    const float* kvnw   = (const float*)d_in[10];
    float* out = (float*)d_out;

    u16* ws = (u16*)d_ws;
    u16* qbuf   = ws + 0;
    u16* wt_qd  = ws + 0;                       // dead before qbuf written (G2)
    u16* kvup   = ws + 12582912;
    u16* hid_bf = ws + 12582912;                // dead before kvup written (G4)
    u16* wt_kvd = ws + 20971520;                // dead before kvup written (G4)
    u16* attnb  = ws + 29360128;
    u16* qd     = ws + 29360128;                // dead before attnb written (attn)
    u16* wt_qu  = ws + 33554432;                // dead before attnb written (attn)
    u16* kvb    = ws + 37748736;
    u16* wt_o   = ws + 37748736;                // written after kvb dead (rope)
    u16* kvn    = ws + 40108032;
    u16* wt_kvu = ws + 42205184;
    u16* krot   = ws + 44302336;                // end: 44,564,480 elems (89.1 MB)

    // hidden f32 -> bf16
    {
        long long n2 = (long long)4096 * 2048 / 2;
        cvt_f32_bf16<<<(int)((n2 + 255) / 256), 256, 0, stream>>>(hidden, hid_bf, n2);
    }

    // q path
    transpose_f32_bf16<<<dim3(32, 64), 256, 0, stream>>>(w_qd, wt_qd, 2048, 1024);
    gemm_bf16<<<dim3(16, 64), 256, 0, stream>>>(hid_bf, wt_qd, qd, 4096, 1024, 2048);
    rmsnorm_kernel<<<4096, 256, 0, stream>>>(qd, qnw, qd, 1024, 1024, 1024);
    transpose_f32_bf16<<<dim3(96, 32), 256, 0, stream>>>(w_qu, wt_qu, 1024, 3072);
    gemm_bf16<<<dim3(48, 64), 256, 0, stream>>>(qd, wt_qu, qbuf, 4096, 3072, 1024);

    // kv path
    transpose_f32_bf16<<<dim3(18, 64), 256, 0, stream>>>(w_kvd, wt_kvd, 2048, 576);
    gemm_bf16<<<dim3(9, 64), 256, 0, stream>>>(hid_bf, wt_kvd, kvb, 4096, 576, 2048);
    rmsnorm_kernel<<<4096, 256, 0, stream>>>(kvb, kvnw, kvn, 512, 576, 512);
    transpose_f32_bf16<<<dim3(128, 16), 256, 0, stream>>>(w_kvu, wt_kvu, 512, 4096);
    gemm_bf16<<<dim3(64, 64), 256, 0, stream>>>(kvn, wt_kvu, kvup, 4096, 4096, 512);

    // rope (q in-place + krot); then wt_o into space freed by kvb/kvn
    rope_kernel<<<4096, 256, 0, stream>>>(qbuf, kvb, krot, cosb, sinb);
    transpose_f32_bf16<<<dim3(64, 64), 256, 0, stream>>>(w_o, wt_o, 2048, 2048);

    // attention
    attn_kernel<<<dim3(64, 16, 2), 256, 0, stream>>>(qbuf, kvup, krot, mask, attnb);

    // output projection -> FLOAT32 output
    gemm_bf16_f32out<<<dim3(32, 64), 256, 0, stream>>>(attnb, wt_o, out, 4096, 2048, 2048);
}

// Round 6
// 1006.899 us; speedup vs baseline: 3.1402x; 3.1402x over previous
//
#include <hip/hip_runtime.h>
#include <hip/hip_bf16.h>

typedef unsigned short u16;
typedef unsigned int u32;
typedef short s16x8 __attribute__((ext_vector_type(8)));
typedef float f32x4 __attribute__((ext_vector_type(4)));
typedef float f32x2 __attribute__((ext_vector_type(2)));

__device__ __forceinline__ float bf2f(u16 u) {
    union { u32 i; float f; } v; v.i = ((u32)u) << 16; return v.f;
}
__device__ __forceinline__ u16 f2bf(float f) {
    union { float f; u32 i; } v; v.f = f;
    u32 i = v.i;
    u32 r = (i + 0x7FFFu + ((i >> 16) & 1u)) >> 16;   // round-to-nearest-even
    return (u16)r;
}

// ---------------------------------------------------------------------------
// Convert f32 -> bf16, 2 elements/thread. n must be even.
// ---------------------------------------------------------------------------
__global__ __launch_bounds__(256) void cvt_f32_bf16(
    const float* __restrict__ in, u16* __restrict__ out, long long n2)
{
    long long i = (long long)blockIdx.x * 256 + threadIdx.x;
    if (i < n2) {
        f32x2 v = *(const f32x2*)(in + i * 2);
        u32 p = (u32)f2bf(v[0]) | ((u32)f2bf(v[1]) << 16);
        *(u32*)(out + i * 2) = p;
    }
}

// ---------------------------------------------------------------------------
// Transpose + convert: f32 in[R][C] -> bf16 out[C][R].  R,C multiples of 32.
// ---------------------------------------------------------------------------
__global__ __launch_bounds__(256) void transpose_f32_bf16(
    const float* __restrict__ in, u16* __restrict__ out, int R, int C)
{
    __shared__ u16 t[32][33];
    int tx = threadIdx.x & 31, ty = threadIdx.x >> 5;   // ty 0..7
    int c0 = blockIdx.x * 32, r0 = blockIdx.y * 32;
    #pragma unroll
    for (int i = 0; i < 32; i += 8)
        t[ty + i][tx] = f2bf(in[(size_t)(r0 + ty + i) * C + c0 + tx]);
    __syncthreads();
    #pragma unroll
    for (int i = 0; i < 32; i += 8)
        out[(size_t)(c0 + ty + i) * R + r0 + tx] = t[tx][ty + i];
}

// ---------------------------------------------------------------------------
// GEMM: C[M][N] = A[M][K] * Bt[N][K]^T   (A,Bt bf16, C bf16, f32 accumulate)
// 64x64 tile, 256 threads = 4 waves (2x2 of 32x32 per wave), K-chunk 32.
// ---------------------------------------------------------------------------
__global__ __launch_bounds__(256) void gemm_bf16(
    const u16* __restrict__ A, const u16* __restrict__ Bt, u16* __restrict__ C,
    int M, int N, int K)
{
    __shared__ u16 As[64][40];
    __shared__ u16 Bs[64][40];

    const int tid  = threadIdx.x;
    const int wave = tid >> 6, lane = tid & 63;
    const int quad = lane >> 4, l16 = lane & 15;
    const int m0 = blockIdx.y * 64, n0 = blockIdx.x * 64;
    const int wm = (wave >> 1) * 32, wn = (wave & 1) * 32;

    const int srow = tid >> 2;            // 0..63
    const int koff = (tid & 3) * 8;       // 0,8,16,24

    f32x4 acc00 = {0.f,0.f,0.f,0.f};
    f32x4 acc01 = {0.f,0.f,0.f,0.f};
    f32x4 acc10 = {0.f,0.f,0.f,0.f};
    f32x4 acc11 = {0.f,0.f,0.f,0.f};

    for (int k0 = 0; k0 < K; k0 += 32) {
        *(s16x8*)&As[srow][koff] = *(const s16x8*)&A[(size_t)(m0 + srow) * K + k0 + koff];
        *(s16x8*)&Bs[srow][koff] = *(const s16x8*)&Bt[(size_t)(n0 + srow) * K + k0 + koff];
        __syncthreads();
        s16x8 a0 = *(const s16x8*)&As[wm + l16][quad * 8];
        s16x8 a1 = *(const s16x8*)&As[wm + 16 + l16][quad * 8];
        s16x8 b0 = *(const s16x8*)&Bs[wn + l16][quad * 8];
        s16x8 b1 = *(const s16x8*)&Bs[wn + 16 + l16][quad * 8];
        acc00 = __builtin_amdgcn_mfma_f32_16x16x32_bf16(a0, b0, acc00, 0, 0, 0);
        acc01 = __builtin_amdgcn_mfma_f32_16x16x32_bf16(a0, b1, acc01, 0, 0, 0);
        acc10 = __builtin_amdgcn_mfma_f32_16x16x32_bf16(a1, b0, acc10, 0, 0, 0);
        acc11 = __builtin_amdgcn_mfma_f32_16x16x32_bf16(a1, b1, acc11, 0, 0, 0);
        __syncthreads();
    }

    #pragma unroll
    for (int r = 0; r < 4; ++r) {
        int row0 = m0 + wm + quad * 4 + r;
        int col0 = n0 + wn + l16;
        C[(size_t)row0 * N + col0]             = f2bf(acc00[r]);
        C[(size_t)row0 * N + col0 + 16]        = f2bf(acc01[r]);
        C[(size_t)(row0 + 16) * N + col0]      = f2bf(acc10[r]);
        C[(size_t)(row0 + 16) * N + col0 + 16] = f2bf(acc11[r]);
    }
}

// ---------------------------------------------------------------------------
// Same GEMM but with FLOAT32 output (final o-projection; d_out is float*).
// ---------------------------------------------------------------------------
__global__ __launch_bounds__(256) void gemm_bf16_f32out(
    const u16* __restrict__ A, const u16* __restrict__ Bt, float* __restrict__ C,
    int M, int N, int K)
{
    __shared__ u16 As[64][40];
    __shared__ u16 Bs[64][40];

    const int tid  = threadIdx.x;
    const int wave = tid >> 6, lane = tid & 63;
    const int quad = lane >> 4, l16 = lane & 15;
    const int m0 = blockIdx.y * 64, n0 = blockIdx.x * 64;
    const int wm = (wave >> 1) * 32, wn = (wave & 1) * 32;

    const int srow = tid >> 2;
    const int koff = (tid & 3) * 8;

    f32x4 acc00 = {0.f,0.f,0.f,0.f};
    f32x4 acc01 = {0.f,0.f,0.f,0.f};
    f32x4 acc10 = {0.f,0.f,0.f,0.f};
    f32x4 acc11 = {0.f,0.f,0.f,0.f};

    for (int k0 = 0; k0 < K; k0 += 32) {
        *(s16x8*)&As[srow][koff] = *(const s16x8*)&A[(size_t)(m0 + srow) * K + k0 + koff];
        *(s16x8*)&Bs[srow][koff] = *(const s16x8*)&Bt[(size_t)(n0 + srow) * K + k0 + koff];
        __syncthreads();
        s16x8 a0 = *(const s16x8*)&As[wm + l16][quad * 8];
        s16x8 a1 = *(const s16x8*)&As[wm + 16 + l16][quad * 8];
        s16x8 b0 = *(const s16x8*)&Bs[wn + l16][quad * 8];
        s16x8 b1 = *(const s16x8*)&Bs[wn + 16 + l16][quad * 8];
        acc00 = __builtin_amdgcn_mfma_f32_16x16x32_bf16(a0, b0, acc00, 0, 0, 0);
        acc01 = __builtin_amdgcn_mfma_f32_16x16x32_bf16(a0, b1, acc01, 0, 0, 0);
        acc10 = __builtin_amdgcn_mfma_f32_16x16x32_bf16(a1, b0, acc10, 0, 0, 0);
        acc11 = __builtin_amdgcn_mfma_f32_16x16x32_bf16(a1, b1, acc11, 0, 0, 0);
        __syncthreads();
    }

    #pragma unroll
    for (int r = 0; r < 4; ++r) {
        int row0 = m0 + wm + quad * 4 + r;
        int col0 = n0 + wn + l16;
        C[(size_t)row0 * N + col0]             = acc00[r];
        C[(size_t)row0 * N + col0 + 16]        = acc01[r];
        C[(size_t)(row0 + 16) * N + col0]      = acc10[r];
        C[(size_t)(row0 + 16) * N + col0 + 16] = acc11[r];
    }
}

// ---------------------------------------------------------------------------
// RMSNorm rows: out = x * rsqrt(mean(x^2)+eps) * w  (x bf16, w f32, out bf16)
// ---------------------------------------------------------------------------
__global__ __launch_bounds__(256) void rmsnorm_kernel(
    const u16* __restrict__ in, const float* __restrict__ w, u16* __restrict__ out,
    int len, int istride, int ostride)
{
    const int row = blockIdx.x, tid = threadIdx.x;
    const u16* x = in + (size_t)row * istride;
    float ss = 0.f;
    for (int i = tid; i < len; i += 256) { float v = bf2f(x[i]); ss += v * v; }
    #pragma unroll
    for (int off = 32; off >= 1; off >>= 1) ss += __shfl_xor(ss, off, 64);
    __shared__ float wsum[4];
    if ((tid & 63) == 0) wsum[tid >> 6] = ss;
    __syncthreads();
    float tot = wsum[0] + wsum[1] + wsum[2] + wsum[3];
    float inv = 1.0f / sqrtf(tot / (float)len + 1e-6f);
    for (int i = tid; i < len; i += 256) {
        float v = bf2f(x[i]);
        out[(size_t)row * ostride + i] = f2bf(v * inv * w[i]);
    }
}

// ---------------------------------------------------------------------------
// RoPE: q rope halves (16 heads, in-place) + k_rope -> krot. cos/sin f32.
// ---------------------------------------------------------------------------
__global__ __launch_bounds__(256) void rope_kernel(
    u16* __restrict__ qb, const u16* __restrict__ kvb, u16* __restrict__ krot,
    const float* __restrict__ cosb, const float* __restrict__ sinb)
{
    const int row = blockIdx.x;
    const int s = row & 2047;
    const int lane = threadIdx.x & 63, wave = threadIdx.x >> 6;
    const float c  = cosb[s * 64 + lane];
    const float sn = sinb[s * 64 + lane];
    for (int seg = wave; seg < 17; seg += 4) {
        const u16* pin; u16* pout;
        if (seg < 16) { pout = qb + (size_t)row * 3072 + seg * 192 + 128; pin = pout; }
        else          { pin = kvb + (size_t)row * 576 + 512; pout = krot + (size_t)row * 64; }
        float x  = bf2f(pin[lane]);
        float xp = bf2f(pin[lane ^ 32]);
        float rot = (lane < 32) ? -xp : xp;
        pout[lane] = f2bf(x * c + rot * sn);
    }
}

// ---------------------------------------------------------------------------
// MFMA flash attention. Block = 256 thr (4 waves); Q-tile 64 rows (16/wave);
// K-tile 64. QK^T and PV on MFMA 16x16x32_bf16 using the fragment layouts
// ref-verified by gemm_bf16 (A/B-frag: n=lane&15,k=quad*8+j from [n][k] LDS;
// C/D: col=lane&15,row=quad*4+reg). Softmax state in registers; P round-trips
// through wave-private LDS rows (no barrier needed). grid = (32, 16, 2).
// ---------------------------------------------------------------------------
__global__ __launch_bounds__(256) void attn_mfma(
    const u16* __restrict__ qb,     // [4096][3072]  (rope applied)
    const u16* __restrict__ kvup,   // [4096][4096]  (per head: 128 nope | 128 v)
    const u16* __restrict__ krot,   // [4096][64]
    const float* __restrict__ mask, // [2][2048]
    u16* __restrict__ attnb)        // [4096][2048]
{
    __shared__ u16 Qs[64][200];   // stride 400B: breaks 16-way row conflict
    __shared__ u16 Ks[64][200];
    __shared__ u16 Vs[128][72];   // V transposed: Vs[v][k'], stride 144B (9x16)
    __shared__ u16 Ps[64][72];    // P round-trip, wave-private rows

    const int tid  = threadIdx.x;
    const int wave = tid >> 6, lane = tid & 63;
    const int quad = lane >> 4, l16 = lane & 15;
    const int qt = blockIdx.x, h = blockIdx.y, b = blockIdx.z;
    const int row0 = b * 2048 + qt * 64;
    const int qw = wave * 16;                   // this wave's q-row base
    const float scale = 0.07216878364870323f;   // 1/sqrt(192)

    // stage Q tile: 64 rows x 192 cols (1536 16B-chunks, 6 per thread)
    #pragma unroll
    for (int i = 0; i < 6; ++i) {
        int idx = tid + i * 256;
        int r = idx / 24, c = (idx % 24) * 8;
        *(s16x8*)&Qs[r][c] = *(const s16x8*)&qb[(size_t)(row0 + r) * 3072 + h * 192 + c];
    }

    float m[4], l[4];
    #pragma unroll
    for (int r = 0; r < 4; ++r) { m[r] = -__builtin_inff(); l[r] = 0.f; }
    f32x4 O[8];
    #pragma unroll
    for (int vt = 0; vt < 8; ++vt) O[vt] = (f32x4){0.f,0.f,0.f,0.f};

    for (int kt = 0; kt < 32; ++kt) {
        const int krow0 = b * 2048 + kt * 64;
        __syncthreads();   // prior iteration's Ks/Vs reads complete
        // stage K tile (nope cols 0..127 from kvup, rope 128..191 from krot)
        #pragma unroll
        for (int i = 0; i < 6; ++i) {
            int idx = tid + i * 256;
            int r = idx / 24, c = (idx % 24) * 8;
            const u16* src = (c < 128)
                ? &kvup[(size_t)(krow0 + r) * 4096 + h * 256 + c]
                : &krot[(size_t)(krow0 + r) * 64 + (c - 128)];
            *(s16x8*)&Ks[r][c] = *(const s16x8*)src;
        }
        // stage V transposed: Vs[v][k']  (coalesced u32 global reads)
        #pragma unroll
        for (int i = 0; i < 16; ++i) {
            int idx = tid + i * 256;               // 0..4095
            int kr = idx >> 6, vp = (idx & 63) * 2;
            u32 vv = *(const u32*)&kvup[(size_t)(krow0 + kr) * 4096 + h * 256 + 128 + vp];
            Vs[vp][kr]     = (u16)(vv & 0xffffu);
            Vs[vp + 1][kr] = (u16)(vv >> 16);
        }
        __syncthreads();

        // ---- QK^T: S[16 q][64 k'] per wave ----
        f32x4 S[4];
        #pragma unroll
        for (int ct = 0; ct < 4; ++ct) S[ct] = (f32x4){0.f,0.f,0.f,0.f};
        #pragma unroll
        for (int kc = 0; kc < 6; ++kc) {
            s16x8 a = *(const s16x8*)&Qs[qw + l16][kc * 32 + quad * 8];
            #pragma unroll
            for (int ct = 0; ct < 4; ++ct) {
                s16x8 bf = *(const s16x8*)&Ks[ct * 16 + l16][kc * 32 + quad * 8];
                S[ct] = __builtin_amdgcn_mfma_f32_16x16x32_bf16(a, bf, S[ct], 0, 0, 0);
            }
        }
        // scale + mask (mask uniform over q-rows; col = kt*64 + ct*16 + l16)
        #pragma unroll
        for (int ct = 0; ct < 4; ++ct) {
            float mv = mask[b * 2048 + kt * 64 + ct * 16 + l16];
            #pragma unroll
            for (int r = 0; r < 4; ++r) S[ct][r] = S[ct][r] * scale + mv;
        }
        // row max over this tile's 64 cols (reduce 4 tiles, then 16 lanes)
        float tmax[4];
        #pragma unroll
        for (int r = 0; r < 4; ++r)
            tmax[r] = fmaxf(fmaxf(S[0][r], S[1][r]), fmaxf(S[2][r], S[3][r]));
        #pragma unroll
        for (int off = 1; off < 16; off <<= 1) {
            #pragma unroll
            for (int r = 0; r < 4; ++r)
                tmax[r] = fmaxf(tmax[r], __shfl_xor(tmax[r], off, 64));
        }
        // online-softmax update
        float alpha[4];
        #pragma unroll
        for (int r = 0; r < 4; ++r) {
            float mn = fmaxf(m[r], tmax[r]);
            alpha[r] = __expf(m[r] - mn);
            m[r] = mn;
        }
        // P = exp(S - m); row sums
        float rsum[4] = {0.f, 0.f, 0.f, 0.f};
        #pragma unroll
        for (int ct = 0; ct < 4; ++ct) {
            #pragma unroll
            for (int r = 0; r < 4; ++r) {
                float p = __expf(S[ct][r] - m[r]);
                S[ct][r] = p;
                rsum[r] += p;
            }
        }
        #pragma unroll
        for (int off = 1; off < 16; off <<= 1) {
            #pragma unroll
            for (int r = 0; r < 4; ++r)
                rsum[r] += __shfl_xor(rsum[r], off, 64);
        }
        #pragma unroll
        for (int r = 0; r < 4; ++r) l[r] = l[r] * alpha[r] + rsum[r];
        // write P (bf16) to wave-private Ps rows; read back as A-fragments.
        // Same-wave RAW: compiler inserts lgkmcnt waits; no barrier needed.
        #pragma unroll
        for (int ct = 0; ct < 4; ++ct) {
            #pragma unroll
            for (int r = 0; r < 4; ++r)
                Ps[qw + quad * 4 + r][ct * 16 + l16] = f2bf(S[ct][r]);
        }
        // rescale O by alpha
        #pragma unroll
        for (int vt = 0; vt < 8; ++vt) {
            #pragma unroll
            for (int r = 0; r < 4; ++r) O[vt][r] *= alpha[r];
        }
        // ---- PV: O[16 q][128 v] += P[16 q][64 k'] * V[64 k'][128 v] ----
        #pragma unroll
        for (int kc = 0; kc < 2; ++kc) {
            s16x8 a = *(const s16x8*)&Ps[qw + l16][kc * 32 + quad * 8];
            #pragma unroll
            for (int vt = 0; vt < 8; ++vt) {
                s16x8 bf = *(const s16x8*)&Vs[vt * 16 + l16][kc * 32 + quad * 8];
                O[vt] = __builtin_amdgcn_mfma_f32_16x16x32_bf16(a, bf, O[vt], 0, 0, 0);
            }
        }
    }

    // epilogue: normalize and store
    float linv[4];
    #pragma unroll
    for (int r = 0; r < 4; ++r) linv[r] = 1.0f / l[r];
    #pragma unroll
    for (int vt = 0; vt < 8; ++vt) {
        #pragma unroll
        for (int r = 0; r < 4; ++r) {
            int q_ = row0 + qw + quad * 4 + r;
            attnb[(size_t)q_ * 2048 + h * 128 + vt * 16 + l16] = f2bf(O[vt][r] * linv[r]);
        }
    }
}

// ---------------------------------------------------------------------------
// Workspace layout (u16 elements) — round-3 lifetime-reuse layout (proven).
// ---------------------------------------------------------------------------
extern "C" void kernel_launch(void* const* d_in, const int* in_sizes, int n_in,
                              void* d_out, int out_size, void* d_ws, size_t ws_size,
                              hipStream_t stream)
{
    // Inputs f32 per the reference; OUTPUT f32 per the reference (d_out = float*).
    const float* hidden = (const float*)d_in[0];
    const float* mask   = (const float*)d_in[1];
    const float* cosb   = (const float*)d_in[2];
    const float* sinb   = (const float*)d_in[3];
    const float* w_qd   = (const float*)d_in[4];
    const float* w_qu   = (const float*)d_in[5];
    const float* w_kvd  = (const float*)d_in[6];
    const float* w_kvu  = (const float*)d_in[7];
    const float* w_o    = (const float*)d_in[8];
    const float* qnw    = (const float*)d_in[9];
    const float* kvnw   = (const float*)d_in[10];
    float* out = (float*)d_out;

    u16* ws = (u16*)d_ws;
    u16* qbuf   = ws + 0;
    u16* wt_qd  = ws + 0;                       // dead before qbuf written (G2)
    u16* kvup   = ws + 12582912;
    u16* hid_bf = ws + 12582912;                // dead before kvup written (G4)
    u16* wt_kvd = ws + 20971520;                // dead before kvup written (G4)
    u16* attnb  = ws + 29360128;
    u16* qd     = ws + 29360128;                // dead before attnb written (attn)
    u16* wt_qu  = ws + 33554432;                // dead before attnb written (attn)
    u16* kvb    = ws + 37748736;
    u16* wt_o   = ws + 37748736;                // written after kvb dead (rope)
    u16* kvn    = ws + 40108032;
    u16* wt_kvu = ws + 42205184;
    u16* krot   = ws + 44302336;                // end: 44,564,480 elems (89.1 MB)

    // hidden f32 -> bf16
    {
        long long n2 = (long long)4096 * 2048 / 2;
        cvt_f32_bf16<<<(int)((n2 + 255) / 256), 256, 0, stream>>>(hidden, hid_bf, n2);
    }

    // q path
    transpose_f32_bf16<<<dim3(32, 64), 256, 0, stream>>>(w_qd, wt_qd, 2048, 1024);
    gemm_bf16<<<dim3(16, 64), 256, 0, stream>>>(hid_bf, wt_qd, qd, 4096, 1024, 2048);
    rmsnorm_kernel<<<4096, 256, 0, stream>>>(qd, qnw, qd, 1024, 1024, 1024);
    transpose_f32_bf16<<<dim3(96, 32), 256, 0, stream>>>(w_qu, wt_qu, 1024, 3072);
    gemm_bf16<<<dim3(48, 64), 256, 0, stream>>>(qd, wt_qu, qbuf, 4096, 3072, 1024);

    // kv path
    transpose_f32_bf16<<<dim3(18, 64), 256, 0, stream>>>(w_kvd, wt_kvd, 2048, 576);
    gemm_bf16<<<dim3(9, 64), 256, 0, stream>>>(hid_bf, wt_kvd, kvb, 4096, 576, 2048);
    rmsnorm_kernel<<<4096, 256, 0, stream>>>(kvb, kvnw, kvn, 512, 576, 512);
    transpose_f32_bf16<<<dim3(128, 16), 256, 0, stream>>>(w_kvu, wt_kvu, 512, 4096);
    gemm_bf16<<<dim3(64, 64), 256, 0, stream>>>(kvn, wt_kvu, kvup, 4096, 4096, 512);

    // rope (q in-place + krot); then wt_o into space freed by kvb/kvn
    rope_kernel<<<4096, 256, 0, stream>>>(qbuf, kvb, krot, cosb, sinb);
    transpose_f32_bf16<<<dim3(64, 64), 256, 0, stream>>>(w_o, wt_o, 2048, 2048);

    // attention (MFMA flash)
    attn_mfma<<<dim3(32, 16, 2), 256, 0, stream>>>(qbuf, kvup, krot, mask, attnb);

    // output projection -> FLOAT32 output
    gemm_bf16_f32out<<<dim3(32, 64), 256, 0, stream>>>(attnb, wt_o, out, 4096, 2048, 2048);
}

// Round 7
// 598.238 us; speedup vs baseline: 5.2853x; 1.6831x over previous
//
#include <hip/hip_runtime.h>
#include <hip/hip_bf16.h>

typedef unsigned short u16;
typedef unsigned int u32;
typedef short s16x8 __attribute__((ext_vector_type(8)));
typedef float f32x4 __attribute__((ext_vector_type(4)));
typedef float f32x2 __attribute__((ext_vector_type(2)));

__device__ __forceinline__ float bf2f(u16 u) {
    union { u32 i; float f; } v; v.i = ((u32)u) << 16; return v.f;
}
__device__ __forceinline__ u16 f2bf(float f) {
    union { float f; u32 i; } v; v.f = f;
    u32 i = v.i;
    u32 r = (i + 0x7FFFu + ((i >> 16) & 1u)) >> 16;   // round-to-nearest-even
    return (u16)r;
}

// async global->LDS, 16 B per lane: dest = lds_base + lane*16 (wave-uniform base)
__device__ __forceinline__ void gl2lds16(const u16* g, u16* l) {
    __builtin_amdgcn_global_load_lds(
        (const __attribute__((address_space(1))) u32*)g,
        (__attribute__((address_space(3))) u32*)l, 16, 0, 0);
}

// ---------------------------------------------------------------------------
// Convert f32 -> bf16, 2 elements/thread.
// ---------------------------------------------------------------------------
__global__ __launch_bounds__(256) void cvt_f32_bf16(
    const float* __restrict__ in, u16* __restrict__ out, long long n2)
{
    long long i = (long long)blockIdx.x * 256 + threadIdx.x;
    if (i < n2) {
        f32x2 v = *(const f32x2*)(in + i * 2);
        u32 p = (u32)f2bf(v[0]) | ((u32)f2bf(v[1]) << 16);
        *(u32*)(out + i * 2) = p;
    }
}

// ---------------------------------------------------------------------------
// Transpose + convert: f32 in[R][C] -> bf16 out[C][R].  R,C multiples of 32.
// ---------------------------------------------------------------------------
__global__ __launch_bounds__(256) void transpose_f32_bf16(
    const float* __restrict__ in, u16* __restrict__ out, int R, int C)
{
    __shared__ u16 t[32][33];
    int tx = threadIdx.x & 31, ty = threadIdx.x >> 5;
    int c0 = blockIdx.x * 32, r0 = blockIdx.y * 32;
    #pragma unroll
    for (int i = 0; i < 32; i += 8)
        t[ty + i][tx] = f2bf(in[(size_t)(r0 + ty + i) * C + c0 + tx]);
    __syncthreads();
    #pragma unroll
    for (int i = 0; i < 32; i += 8)
        out[(size_t)(c0 + ty + i) * R + r0 + tx] = t[tx][ty + i];
}

// ---------------------------------------------------------------------------
// V transpose: kvup V-half -> vt[b][h][v][s]  (bf16 -> bf16, 32x32 LDS tiles)
// grid = (64 s-tiles, 4 v-tiles, 32 bh), block = 256
// ---------------------------------------------------------------------------
__global__ __launch_bounds__(256) void transpose_v(
    const u16* __restrict__ kvup, u16* __restrict__ vt)
{
    __shared__ u16 t[32][33];
    int tx = threadIdx.x & 31, ty = threadIdx.x >> 5;
    int s0 = blockIdx.x * 32, v0 = blockIdx.y * 32;
    int b = blockIdx.z >> 4, h = blockIdx.z & 15;
    #pragma unroll
    for (int i = 0; i < 32; i += 8)
        t[ty + i][tx] = kvup[(size_t)(b * 2048 + s0 + ty + i) * 4096 + h * 256 + 128 + v0 + tx];
    __syncthreads();
    #pragma unroll
    for (int i = 0; i < 32; i += 8)
        vt[((size_t)(b * 16 + h) * 128 + v0 + ty + i) * 2048 + s0 + tx] = t[tx][ty + i];
}

// ---------------------------------------------------------------------------
// GEMM 64x64 tile (kept for kv_down: N=576 not /128).
// ---------------------------------------------------------------------------
__global__ __launch_bounds__(256) void gemm_bf16(
    const u16* __restrict__ A, const u16* __restrict__ Bt, u16* __restrict__ C,
    int M, int N, int K)
{
    __shared__ u16 As[64][40];
    __shared__ u16 Bs[64][40];

    const int tid  = threadIdx.x;
    const int wave = tid >> 6, lane = tid & 63;
    const int quad = lane >> 4, l16 = lane & 15;
    const int m0 = blockIdx.y * 64, n0 = blockIdx.x * 64;
    const int wm = (wave >> 1) * 32, wn = (wave & 1) * 32;

    const int srow = tid >> 2;
    const int koff = (tid & 3) * 8;

    f32x4 acc00 = {0.f,0.f,0.f,0.f};
    f32x4 acc01 = {0.f,0.f,0.f,0.f};
    f32x4 acc10 = {0.f,0.f,0.f,0.f};
    f32x4 acc11 = {0.f,0.f,0.f,0.f};

    for (int k0 = 0; k0 < K; k0 += 32) {
        *(s16x8*)&As[srow][koff] = *(const s16x8*)&A[(size_t)(m0 + srow) * K + k0 + koff];
        *(s16x8*)&Bs[srow][koff] = *(const s16x8*)&Bt[(size_t)(n0 + srow) * K + k0 + koff];
        __syncthreads();
        s16x8 a0 = *(const s16x8*)&As[wm + l16][quad * 8];
        s16x8 a1 = *(const s16x8*)&As[wm + 16 + l16][quad * 8];
        s16x8 b0 = *(const s16x8*)&Bs[wn + l16][quad * 8];
        s16x8 b1 = *(const s16x8*)&Bs[wn + 16 + l16][quad * 8];
        acc00 = __builtin_amdgcn_mfma_f32_16x16x32_bf16(a0, b0, acc00, 0, 0, 0);
        acc01 = __builtin_amdgcn_mfma_f32_16x16x32_bf16(a0, b1, acc01, 0, 0, 0);
        acc10 = __builtin_amdgcn_mfma_f32_16x16x32_bf16(a1, b0, acc10, 0, 0, 0);
        acc11 = __builtin_amdgcn_mfma_f32_16x16x32_bf16(a1, b1, acc11, 0, 0, 0);
        __syncthreads();
    }

    #pragma unroll
    for (int r = 0; r < 4; ++r) {
        int row0 = m0 + wm + quad * 4 + r;
        int col0 = n0 + wn + l16;
        C[(size_t)row0 * N + col0]             = f2bf(acc00[r]);
        C[(size_t)row0 * N + col0 + 16]        = f2bf(acc01[r]);
        C[(size_t)(row0 + 16) * N + col0]      = f2bf(acc10[r]);
        C[(size_t)(row0 + 16) * N + col0 + 16] = f2bf(acc11[r]);
    }
}

// ---------------------------------------------------------------------------
// GEMM 128x128 tile (m97 structure): 4 waves, each 64x64 via 4x4 of 16x16;
// BK=32; global_load_lds width-16 staging into unpadded row-major LDS.
// M,N % 128 == 0, K % 32 == 0. OUT = u16 (bf16) or float.
// ---------------------------------------------------------------------------
template <typename OUT>
__global__ __launch_bounds__(256) void gemm128(
    const u16* __restrict__ A, const u16* __restrict__ Bt, OUT* __restrict__ C,
    int M, int N, int K)
{
    __shared__ u16 As[128 * 32];   // row-major [128][32], unpadded (async dest)
    __shared__ u16 Bs[128 * 32];

    const int tid  = threadIdx.x;
    const int wave = tid >> 6, lane = tid & 63;
    const int quad = lane >> 4, l16 = lane & 15;
    const int m0 = blockIdx.y * 128, n0 = blockIdx.x * 128;
    const int wm = (wave >> 1) * 64, wn = (wave & 1) * 64;

    // staging: op g = wave*2+op covers rows g*16..+15; lane -> row g*16+lane/4,
    // k-octet (lane&3)*8  (matches HW dest = base + lane*16)
    const int srow = lane >> 2, soct = (lane & 3) * 8;

    f32x4 acc[4][4];
    #pragma unroll
    for (int i = 0; i < 4; ++i)
        #pragma unroll
        for (int j = 0; j < 4; ++j) acc[i][j] = (f32x4){0.f,0.f,0.f,0.f};

    for (int k0 = 0; k0 < K; k0 += 32) {
        #pragma unroll
        for (int op = 0; op < 2; ++op) {
            int g = wave * 2 + op;
            gl2lds16(&A[(size_t)(m0 + g * 16 + srow) * K + k0 + soct], &As[g * 512]);
            gl2lds16(&Bt[(size_t)(n0 + g * 16 + srow) * K + k0 + soct], &Bs[g * 512]);
        }
        __syncthreads();   // drains vmcnt (async LDS writes) + all waves staged
        s16x8 af[4], bf[4];
        #pragma unroll
        for (int i = 0; i < 4; ++i) {
            af[i] = *(const s16x8*)&As[(wm + i * 16 + l16) * 32 + quad * 8];
            bf[i] = *(const s16x8*)&Bs[(wn + i * 16 + l16) * 32 + quad * 8];
        }
        #pragma unroll
        for (int i = 0; i < 4; ++i)
            #pragma unroll
            for (int j = 0; j < 4; ++j)
                acc[i][j] = __builtin_amdgcn_mfma_f32_16x16x32_bf16(af[i], bf[j], acc[i][j], 0, 0, 0);
        __syncthreads();   // reads done before next stage
    }

    #pragma unroll
    for (int i = 0; i < 4; ++i) {
        #pragma unroll
        for (int j = 0; j < 4; ++j) {
            #pragma unroll
            for (int r = 0; r < 4; ++r) {
                int row = m0 + wm + i * 16 + quad * 4 + r;
                int col = n0 + wn + j * 16 + l16;
                if constexpr (sizeof(OUT) == 2)
                    C[(size_t)row * N + col] = f2bf(acc[i][j][r]);
                else
                    C[(size_t)row * N + col] = acc[i][j][r];
            }
        }
    }
}

// ---------------------------------------------------------------------------
// RMSNorm rows: out = x * rsqrt(mean(x^2)+eps) * w  (x bf16, w f32, out bf16)
// ---------------------------------------------------------------------------
__global__ __launch_bounds__(256) void rmsnorm_kernel(
    const u16* __restrict__ in, const float* __restrict__ w, u16* __restrict__ out,
    int len, int istride, int ostride)
{
    const int row = blockIdx.x, tid = threadIdx.x;
    const u16* x = in + (size_t)row * istride;
    float ss = 0.f;
    for (int i = tid; i < len; i += 256) { float v = bf2f(x[i]); ss += v * v; }
    #pragma unroll
    for (int off = 32; off >= 1; off >>= 1) ss += __shfl_xor(ss, off, 64);
    __shared__ float wsum[4];
    if ((tid & 63) == 0) wsum[tid >> 6] = ss;
    __syncthreads();
    float tot = wsum[0] + wsum[1] + wsum[2] + wsum[3];
    float inv = 1.0f / sqrtf(tot / (float)len + 1e-6f);
    for (int i = tid; i < len; i += 256) {
        float v = bf2f(x[i]);
        out[(size_t)row * ostride + i] = f2bf(v * inv * w[i]);
    }
}

// ---------------------------------------------------------------------------
// RoPE: q rope halves (16 heads, in-place) + k_rope -> krot. cos/sin f32.
// ---------------------------------------------------------------------------
__global__ __launch_bounds__(256) void rope_kernel(
    u16* __restrict__ qb, const u16* __restrict__ kvb, u16* __restrict__ krot,
    const float* __restrict__ cosb, const float* __restrict__ sinb)
{
    const int row = blockIdx.x;
    const int s = row & 2047;
    const int lane = threadIdx.x & 63, wave = threadIdx.x >> 6;
    const float c  = cosb[s * 64 + lane];
    const float sn = sinb[s * 64 + lane];
    for (int seg = wave; seg < 17; seg += 4) {
        const u16* pin; u16* pout;
        if (seg < 16) { pout = qb + (size_t)row * 3072 + seg * 192 + 128; pin = pout; }
        else          { pin = kvb + (size_t)row * 576 + 512; pout = krot + (size_t)row * 64; }
        float x  = bf2f(pin[lane]);
        float xp = bf2f(pin[lane ^ 32]);
        float rot = (lane < 32) ? -xp : xp;
        pout[lane] = f2bf(x * c + rot * sn);
    }
}

// ---------------------------------------------------------------------------
// MFMA flash attention v2. 4 waves; Q-tile 64 (16/wave, fragments in REGS);
// K-tile 64; V staged from pre-transposed vt (conflict-free b128 rows).
// LDS 53.2 KB -> 3 blocks/CU. grid = (32, 16, 2).
// ---------------------------------------------------------------------------
__global__ __launch_bounds__(256) void attn_mfma2(
    const u16* __restrict__ qb,     // [4096][3072]  (rope applied)
    const u16* __restrict__ kvup,   // [4096][4096]  (per head: 128 nope | 128 v)
    const u16* __restrict__ krot,   // [4096][64]
    const u16* __restrict__ vt,     // [2][16][128][2048]  V transposed
    const float* __restrict__ mask, // [2][2048]
    u16* __restrict__ attnb)        // [4096][2048]
{
    __shared__ u16 Ks[64][200];   // stride 400B
    __shared__ u16 Vs[128][72];   // [v][k'], stride 144B
    __shared__ u16 Ps[64][72];    // P round-trip, wave-private rows

    const int tid  = threadIdx.x;
    const int wave = tid >> 6, lane = tid & 63;
    const int quad = lane >> 4, l16 = lane & 15;
    const int qt = blockIdx.x, h = blockIdx.y, b = blockIdx.z;
    const int row0 = b * 2048 + qt * 64;
    const int qw = wave * 16;
    const float scale = 0.07216878364870323f;   // 1/sqrt(192)

    // Q fragments in registers: lane l16 -> q-row qw+l16, quad -> k-octet
    s16x8 qf[6];
    #pragma unroll
    for (int kc = 0; kc < 6; ++kc)
        qf[kc] = *(const s16x8*)&qb[(size_t)(row0 + qw + l16) * 3072 + h * 192 + kc * 32 + quad * 8];

    float m[4], l[4];
    #pragma unroll
    for (int r = 0; r < 4; ++r) { m[r] = -__builtin_inff(); l[r] = 0.f; }
    f32x4 O[8];
    #pragma unroll
    for (int vi = 0; vi < 8; ++vi) O[vi] = (f32x4){0.f,0.f,0.f,0.f};

    const u16* vtb = vt + ((size_t)(b * 16 + h) * 128) * 2048;

    for (int kt = 0; kt < 32; ++kt) {
        const int krow0 = b * 2048 + kt * 64;
        __syncthreads();   // prior iteration's Ks/Vs reads complete
        // stage K tile (64 x 192): nope from kvup, rope from krot
        #pragma unroll
        for (int i = 0; i < 6; ++i) {
            int idx = tid + i * 256;
            int r = idx / 24, c = (idx % 24) * 8;
            const u16* src = (c < 128)
                ? &kvup[(size_t)(krow0 + r) * 4096 + h * 256 + c]
                : &krot[(size_t)(krow0 + r) * 64 + (c - 128)];
            *(s16x8*)&Ks[r][c] = *(const s16x8*)src;
        }
        // stage V tile from vt: rows contiguous, b128 writes
        #pragma unroll
        for (int i = 0; i < 4; ++i) {
            int idx = tid + i * 256;              // 0..1023
            int r = idx >> 3, c8 = (idx & 7) * 8;
            *(s16x8*)&Vs[r][c8] = *(const s16x8*)&vtb[(size_t)r * 2048 + kt * 64 + c8];
        }
        __syncthreads();

        // ---- QK^T: S[16 q][64 k'] per wave ----
        f32x4 S[4];
        #pragma unroll
        for (int ct = 0; ct < 4; ++ct) S[ct] = (f32x4){0.f,0.f,0.f,0.f};
        #pragma unroll
        for (int kc = 0; kc < 6; ++kc) {
            #pragma unroll
            for (int ct = 0; ct < 4; ++ct) {
                s16x8 bf = *(const s16x8*)&Ks[ct * 16 + l16][kc * 32 + quad * 8];
                S[ct] = __builtin_amdgcn_mfma_f32_16x16x32_bf16(qf[kc], bf, S[ct], 0, 0, 0);
            }
        }
        // scale + mask
        #pragma unroll
        for (int ct = 0; ct < 4; ++ct) {
            float mv = mask[b * 2048 + kt * 64 + ct * 16 + l16];
            #pragma unroll
            for (int r = 0; r < 4; ++r) S[ct][r] = S[ct][r] * scale + mv;
        }
        // row max
        float tmax[4];
        #pragma unroll
        for (int r = 0; r < 4; ++r)
            tmax[r] = fmaxf(fmaxf(S[0][r], S[1][r]), fmaxf(S[2][r], S[3][r]));
        #pragma unroll
        for (int off = 1; off < 16; off <<= 1) {
            #pragma unroll
            for (int r = 0; r < 4; ++r)
                tmax[r] = fmaxf(tmax[r], __shfl_xor(tmax[r], off, 64));
        }
        float alpha[4];
        #pragma unroll
        for (int r = 0; r < 4; ++r) {
            float mn = fmaxf(m[r], tmax[r]);
            alpha[r] = __expf(m[r] - mn);
            m[r] = mn;
        }
        float rsum[4] = {0.f, 0.f, 0.f, 0.f};
        #pragma unroll
        for (int ct = 0; ct < 4; ++ct) {
            #pragma unroll
            for (int r = 0; r < 4; ++r) {
                float p = __expf(S[ct][r] - m[r]);
                S[ct][r] = p;
                rsum[r] += p;
            }
        }
        #pragma unroll
        for (int off = 1; off < 16; off <<= 1) {
            #pragma unroll
            for (int r = 0; r < 4; ++r)
                rsum[r] += __shfl_xor(rsum[r], off, 64);
        }
        #pragma unroll
        for (int r = 0; r < 4; ++r) l[r] = l[r] * alpha[r] + rsum[r];
        // P (bf16) -> wave-private Ps rows (same-wave RAW; no barrier needed)
        #pragma unroll
        for (int ct = 0; ct < 4; ++ct) {
            #pragma unroll
            for (int r = 0; r < 4; ++r)
                Ps[qw + quad * 4 + r][ct * 16 + l16] = f2bf(S[ct][r]);
        }
        // rescale O
        #pragma unroll
        for (int vi = 0; vi < 8; ++vi) {
            #pragma unroll
            for (int r = 0; r < 4; ++r) O[vi][r] *= alpha[r];
        }
        // ---- PV ----
        #pragma unroll
        for (int kc = 0; kc < 2; ++kc) {
            s16x8 a = *(const s16x8*)&Ps[qw + l16][kc * 32 + quad * 8];
            #pragma unroll
            for (int vi = 0; vi < 8; ++vi) {
                s16x8 bf = *(const s16x8*)&Vs[vi * 16 + l16][kc * 32 + quad * 8];
                O[vi] = __builtin_amdgcn_mfma_f32_16x16x32_bf16(a, bf, O[vi], 0, 0, 0);
            }
        }
    }

    float linv[4];
    #pragma unroll
    for (int r = 0; r < 4; ++r) linv[r] = 1.0f / l[r];
    #pragma unroll
    for (int vi = 0; vi < 8; ++vi) {
        #pragma unroll
        for (int r = 0; r < 4; ++r) {
            int q_ = row0 + qw + quad * 4 + r;
            attnb[(size_t)q_ * 2048 + h * 128 + vi * 16 + l16] = f2bf(O[vi][r] * linv[r]);
        }
    }
}

// ---------------------------------------------------------------------------
// Workspace layout (u16 elements): round-3 layout + vt at the end (122.7 MB;
// 135.5 MB proven to fit in round 2/3).
// ---------------------------------------------------------------------------
extern "C" void kernel_launch(void* const* d_in, const int* in_sizes, int n_in,
                              void* d_out, int out_size, void* d_ws, size_t ws_size,
                              hipStream_t stream)
{
    const float* hidden = (const float*)d_in[0];
    const float* mask   = (const float*)d_in[1];
    const float* cosb   = (const float*)d_in[2];
    const float* sinb   = (const float*)d_in[3];
    const float* w_qd   = (const float*)d_in[4];
    const float* w_qu   = (const float*)d_in[5];
    const float* w_kvd  = (const float*)d_in[6];
    const float* w_kvu  = (const float*)d_in[7];
    const float* w_o    = (const float*)d_in[8];
    const float* qnw    = (const float*)d_in[9];
    const float* kvnw   = (const float*)d_in[10];
    float* out = (float*)d_out;

    u16* ws = (u16*)d_ws;
    u16* qbuf   = ws + 0;
    u16* wt_qd  = ws + 0;                       // dead before qbuf written
    u16* kvup   = ws + 12582912;
    u16* hid_bf = ws + 12582912;                // dead before kvup written
    u16* wt_kvd = ws + 20971520;                // dead before kvup written
    u16* attnb  = ws + 29360128;
    u16* qd     = ws + 29360128;                // dead before attnb written
    u16* wt_qu  = ws + 33554432;                // dead before attnb written
    u16* kvb    = ws + 37748736;
    u16* wt_o   = ws + 37748736;                // written after kvb dead (rope)
    u16* kvn    = ws + 40108032;
    u16* wt_kvu = ws + 42205184;
    u16* krot   = ws + 44302336;
    u16* vt     = ws + 44564480;                // 16,777,216 elems; end 122.7 MB

    // hidden f32 -> bf16
    {
        long long n2 = (long long)4096 * 2048 / 2;
        cvt_f32_bf16<<<(int)((n2 + 255) / 256), 256, 0, stream>>>(hidden, hid_bf, n2);
    }

    // q path
    transpose_f32_bf16<<<dim3(32, 64), 256, 0, stream>>>(w_qd, wt_qd, 2048, 1024);
    gemm128<u16><<<dim3(8, 32), 256, 0, stream>>>(hid_bf, wt_qd, qd, 4096, 1024, 2048);
    rmsnorm_kernel<<<4096, 256, 0, stream>>>(qd, qnw, qd, 1024, 1024, 1024);
    transpose_f32_bf16<<<dim3(96, 32), 256, 0, stream>>>(w_qu, wt_qu, 1024, 3072);
    gemm128<u16><<<dim3(24, 32), 256, 0, stream>>>(qd, wt_qu, qbuf, 4096, 3072, 1024);

    // kv path
    transpose_f32_bf16<<<dim3(18, 64), 256, 0, stream>>>(w_kvd, wt_kvd, 2048, 576);
    gemm_bf16<<<dim3(9, 64), 256, 0, stream>>>(hid_bf, wt_kvd, kvb, 4096, 576, 2048);
    rmsnorm_kernel<<<4096, 256, 0, stream>>>(kvb, kvnw, kvn, 512, 576, 512);
    transpose_f32_bf16<<<dim3(128, 16), 256, 0, stream>>>(w_kvu, wt_kvu, 512, 4096);
    gemm128<u16><<<dim3(32, 32), 256, 0, stream>>>(kvn, wt_kvu, kvup, 4096, 4096, 512);

    // V transpose for attention staging
    transpose_v<<<dim3(64, 4, 32), 256, 0, stream>>>(kvup, vt);

    // rope (q in-place + krot); then wt_o into space freed by kvb/kvn
    rope_kernel<<<4096, 256, 0, stream>>>(qbuf, kvb, krot, cosb, sinb);
    transpose_f32_bf16<<<dim3(64, 64), 256, 0, stream>>>(w_o, wt_o, 2048, 2048);

    // attention (MFMA flash v2)
    attn_mfma2<<<dim3(32, 16, 2), 256, 0, stream>>>(qbuf, kvup, krot, vt, mask, attnb);

    // output projection -> FLOAT32 output
    gemm128<float><<<dim3(16, 32), 256, 0, stream>>>(attnb, wt_o, out, 4096, 2048, 2048);
}

// Round 8
// 520.308 us; speedup vs baseline: 6.0769x; 1.1498x over previous
//
#include <hip/hip_runtime.h>
#include <hip/hip_bf16.h>

typedef unsigned short u16;
typedef unsigned int u32;
typedef short s16x8 __attribute__((ext_vector_type(8)));
typedef float f32x4 __attribute__((ext_vector_type(4)));
typedef float f32x2 __attribute__((ext_vector_type(2)));

__device__ __forceinline__ float bf2f(u16 u) {
    union { u32 i; float f; } v; v.i = ((u32)u) << 16; return v.f;
}
__device__ __forceinline__ u16 f2bf(float f) {
    union { float f; u32 i; } v; v.f = f;
    u32 i = v.i;
    u32 r = (i + 0x7FFFu + ((i >> 16) & 1u)) >> 16;   // round-to-nearest-even
    return (u16)r;
}

// async global->LDS, 16 B per lane: dest = lds_base + lane*16 (wave-uniform base)
__device__ __forceinline__ void gl2lds16(const u16* g, u16* l) {
    __builtin_amdgcn_global_load_lds(
        (const __attribute__((address_space(1))) u32*)g,
        (__attribute__((address_space(3))) u32*)l, 16, 0, 0);
}

// ---------------------------------------------------------------------------
// Convert f32 -> bf16, 2 elements/thread.
// ---------------------------------------------------------------------------
__global__ __launch_bounds__(256) void cvt_f32_bf16(
    const float* __restrict__ in, u16* __restrict__ out, long long n2)
{
    long long i = (long long)blockIdx.x * 256 + threadIdx.x;
    if (i < n2) {
        f32x2 v = *(const f32x2*)(in + i * 2);
        u32 p = (u32)f2bf(v[0]) | ((u32)f2bf(v[1]) << 16);
        *(u32*)(out + i * 2) = p;
    }
}

// ---------------------------------------------------------------------------
// Transpose + convert: f32 in[R][C] -> bf16 out[C][R].  R,C multiples of 32.
// ---------------------------------------------------------------------------
__global__ __launch_bounds__(256) void transpose_f32_bf16(
    const float* __restrict__ in, u16* __restrict__ out, int R, int C)
{
    __shared__ u16 t[32][33];
    int tx = threadIdx.x & 31, ty = threadIdx.x >> 5;
    int c0 = blockIdx.x * 32, r0 = blockIdx.y * 32;
    #pragma unroll
    for (int i = 0; i < 32; i += 8)
        t[ty + i][tx] = f2bf(in[(size_t)(r0 + ty + i) * C + c0 + tx]);
    __syncthreads();
    #pragma unroll
    for (int i = 0; i < 32; i += 8)
        out[(size_t)(c0 + ty + i) * R + r0 + tx] = t[tx][ty + i];
}

// ---------------------------------------------------------------------------
// V transpose: kvup V-half -> vt[b][h][v][s]  (bf16 -> bf16, 32x32 LDS tiles)
// grid = (64 s-tiles, 4 v-tiles, 32 bh), block = 256
// ---------------------------------------------------------------------------
__global__ __launch_bounds__(256) void transpose_v(
    const u16* __restrict__ kvup, u16* __restrict__ vt)
{
    __shared__ u16 t[32][33];
    int tx = threadIdx.x & 31, ty = threadIdx.x >> 5;
    int s0 = blockIdx.x * 32, v0 = blockIdx.y * 32;
    int b = blockIdx.z >> 4, h = blockIdx.z & 15;
    #pragma unroll
    for (int i = 0; i < 32; i += 8)
        t[ty + i][tx] = kvup[(size_t)(b * 2048 + s0 + ty + i) * 4096 + h * 256 + 128 + v0 + tx];
    __syncthreads();
    #pragma unroll
    for (int i = 0; i < 32; i += 8)
        vt[((size_t)(b * 16 + h) * 128 + v0 + ty + i) * 2048 + s0 + tx] = t[tx][ty + i];
}

// ---------------------------------------------------------------------------
// GEMM 64x64 tile (kept for kv_down: N=576 not /128).
// ---------------------------------------------------------------------------
__global__ __launch_bounds__(256) void gemm_bf16(
    const u16* __restrict__ A, const u16* __restrict__ Bt, u16* __restrict__ C,
    int M, int N, int K)
{
    __shared__ u16 As[64][40];
    __shared__ u16 Bs[64][40];

    const int tid  = threadIdx.x;
    const int wave = tid >> 6, lane = tid & 63;
    const int quad = lane >> 4, l16 = lane & 15;
    const int m0 = blockIdx.y * 64, n0 = blockIdx.x * 64;
    const int wm = (wave >> 1) * 32, wn = (wave & 1) * 32;

    const int srow = tid >> 2;
    const int koff = (tid & 3) * 8;

    f32x4 acc00 = {0.f,0.f,0.f,0.f};
    f32x4 acc01 = {0.f,0.f,0.f,0.f};
    f32x4 acc10 = {0.f,0.f,0.f,0.f};
    f32x4 acc11 = {0.f,0.f,0.f,0.f};

    for (int k0 = 0; k0 < K; k0 += 32) {
        *(s16x8*)&As[srow][koff] = *(const s16x8*)&A[(size_t)(m0 + srow) * K + k0 + koff];
        *(s16x8*)&Bs[srow][koff] = *(const s16x8*)&Bt[(size_t)(n0 + srow) * K + k0 + koff];
        __syncthreads();
        s16x8 a0 = *(const s16x8*)&As[wm + l16][quad * 8];
        s16x8 a1 = *(const s16x8*)&As[wm + 16 + l16][quad * 8];
        s16x8 b0 = *(const s16x8*)&Bs[wn + l16][quad * 8];
        s16x8 b1 = *(const s16x8*)&Bs[wn + 16 + l16][quad * 8];
        acc00 = __builtin_amdgcn_mfma_f32_16x16x32_bf16(a0, b0, acc00, 0, 0, 0);
        acc01 = __builtin_amdgcn_mfma_f32_16x16x32_bf16(a0, b1, acc01, 0, 0, 0);
        acc10 = __builtin_amdgcn_mfma_f32_16x16x32_bf16(a1, b0, acc10, 0, 0, 0);
        acc11 = __builtin_amdgcn_mfma_f32_16x16x32_bf16(a1, b1, acc11, 0, 0, 0);
        __syncthreads();
    }

    #pragma unroll
    for (int r = 0; r < 4; ++r) {
        int row0 = m0 + wm + quad * 4 + r;
        int col0 = n0 + wn + l16;
        C[(size_t)row0 * N + col0]             = f2bf(acc00[r]);
        C[(size_t)row0 * N + col0 + 16]        = f2bf(acc01[r]);
        C[(size_t)(row0 + 16) * N + col0]      = f2bf(acc10[r]);
        C[(size_t)(row0 + 16) * N + col0 + 16] = f2bf(acc11[r]);
    }
}

// ---------------------------------------------------------------------------
// GEMM 128x128 tile (m97 structure): 4 waves, each 64x64 via 4x4 of 16x16;
// BK=32; global_load_lds width-16 staging into unpadded row-major LDS.
// ---------------------------------------------------------------------------
template <typename OUT>
__global__ __launch_bounds__(256) void gemm128(
    const u16* __restrict__ A, const u16* __restrict__ Bt, OUT* __restrict__ C,
    int M, int N, int K)
{
    __shared__ u16 As[128 * 32];
    __shared__ u16 Bs[128 * 32];

    const int tid  = threadIdx.x;
    const int wave = tid >> 6, lane = tid & 63;
    const int quad = lane >> 4, l16 = lane & 15;
    const int m0 = blockIdx.y * 128, n0 = blockIdx.x * 128;
    const int wm = (wave >> 1) * 64, wn = (wave & 1) * 64;

    const int srow = lane >> 2, soct = (lane & 3) * 8;

    f32x4 acc[4][4];
    #pragma unroll
    for (int i = 0; i < 4; ++i)
        #pragma unroll
        for (int j = 0; j < 4; ++j) acc[i][j] = (f32x4){0.f,0.f,0.f,0.f};

    for (int k0 = 0; k0 < K; k0 += 32) {
        #pragma unroll
        for (int op = 0; op < 2; ++op) {
            int g = wave * 2 + op;
            gl2lds16(&A[(size_t)(m0 + g * 16 + srow) * K + k0 + soct], &As[g * 512]);
            gl2lds16(&Bt[(size_t)(n0 + g * 16 + srow) * K + k0 + soct], &Bs[g * 512]);
        }
        __syncthreads();
        s16x8 af[4], bf[4];
        #pragma unroll
        for (int i = 0; i < 4; ++i) {
            af[i] = *(const s16x8*)&As[(wm + i * 16 + l16) * 32 + quad * 8];
            bf[i] = *(const s16x8*)&Bs[(wn + i * 16 + l16) * 32 + quad * 8];
        }
        #pragma unroll
        for (int i = 0; i < 4; ++i)
            #pragma unroll
            for (int j = 0; j < 4; ++j)
                acc[i][j] = __builtin_amdgcn_mfma_f32_16x16x32_bf16(af[i], bf[j], acc[i][j], 0, 0, 0);
        __syncthreads();
    }

    #pragma unroll
    for (int i = 0; i < 4; ++i) {
        #pragma unroll
        for (int j = 0; j < 4; ++j) {
            #pragma unroll
            for (int r = 0; r < 4; ++r) {
                int row = m0 + wm + i * 16 + quad * 4 + r;
                int col = n0 + wn + j * 16 + l16;
                if constexpr (sizeof(OUT) == 2)
                    C[(size_t)row * N + col] = f2bf(acc[i][j][r]);
                else
                    C[(size_t)row * N + col] = acc[i][j][r];
            }
        }
    }
}

// ---------------------------------------------------------------------------
// RMSNorm rows: out = x * rsqrt(mean(x^2)+eps) * w  (x bf16, w f32, out bf16)
// ---------------------------------------------------------------------------
__global__ __launch_bounds__(256) void rmsnorm_kernel(
    const u16* __restrict__ in, const float* __restrict__ w, u16* __restrict__ out,
    int len, int istride, int ostride)
{
    const int row = blockIdx.x, tid = threadIdx.x;
    const u16* x = in + (size_t)row * istride;
    float ss = 0.f;
    for (int i = tid; i < len; i += 256) { float v = bf2f(x[i]); ss += v * v; }
    #pragma unroll
    for (int off = 32; off >= 1; off >>= 1) ss += __shfl_xor(ss, off, 64);
    __shared__ float wsum[4];
    if ((tid & 63) == 0) wsum[tid >> 6] = ss;
    __syncthreads();
    float tot = wsum[0] + wsum[1] + wsum[2] + wsum[3];
    float inv = 1.0f / sqrtf(tot / (float)len + 1e-6f);
    for (int i = tid; i < len; i += 256) {
        float v = bf2f(x[i]);
        out[(size_t)row * ostride + i] = f2bf(v * inv * w[i]);
    }
}

// ---------------------------------------------------------------------------
// RoPE: q rope halves (16 heads, in-place) + k_rope -> krot. cos/sin f32.
// ---------------------------------------------------------------------------
__global__ __launch_bounds__(256) void rope_kernel(
    u16* __restrict__ qb, const u16* __restrict__ kvb, u16* __restrict__ krot,
    const float* __restrict__ cosb, const float* __restrict__ sinb)
{
    const int row = blockIdx.x;
    const int s = row & 2047;
    const int lane = threadIdx.x & 63, wave = threadIdx.x >> 6;
    const float c  = cosb[s * 64 + lane];
    const float sn = sinb[s * 64 + lane];
    for (int seg = wave; seg < 17; seg += 4) {
        const u16* pin; u16* pout;
        if (seg < 16) { pout = qb + (size_t)row * 3072 + seg * 192 + 128; pin = pout; }
        else          { pin = kvb + (size_t)row * 576 + 512; pout = krot + (size_t)row * 64; }
        float x  = bf2f(pin[lane]);
        float xp = bf2f(pin[lane ^ 32]);
        float rot = (lane < 32) ? -xp : xp;
        pout[lane] = f2bf(x * c + rot * sn);
    }
}

// ---------------------------------------------------------------------------
// MFMA flash attention v3. 4 waves; Q-tile 128 (2 subtiles of 16 rows/wave,
// Q-frags in regs); K-tile 64. Ks/Vs fragment reads shared across subtiles.
// Row-sums via MFMA-with-ones (no sum shuffles); wave-shared running max
// (1 scalar m/wave — valid upper bound for online softmax, 6 shuffles/tile).
// LDS 62.5 KB; grid = (16, 16, 2) = 512 blocks = 2/CU resident.
// ---------------------------------------------------------------------------
__global__ __launch_bounds__(256, 2) void attn_mfma3(
    const u16* __restrict__ qb,     // [4096][3072]  (rope applied)
    const u16* __restrict__ kvup,   // [4096][4096]  (per head: 128 nope | 128 v)
    const u16* __restrict__ krot,   // [4096][64]
    const u16* __restrict__ vt,     // [2][16][128][2048]  V transposed
    const float* __restrict__ mask, // [2][2048]
    u16* __restrict__ attnb)        // [4096][2048]
{
    __shared__ u16 Ks[64][200];    // stride 400B
    __shared__ u16 Vs[128][72];    // [v][k'], stride 144B
    __shared__ u16 Ps[128][72];    // P round-trip, wave-private rows (both subtiles)

    const int tid  = threadIdx.x;
    const int wave = tid >> 6, lane = tid & 63;
    const int quad = lane >> 4, l16 = lane & 15;
    const int qt = blockIdx.x, h = blockIdx.y, b = blockIdx.z;
    const int row0 = b * 2048 + qt * 128;
    const int qw = wave * 16;
    const float scale = 0.07216878364870323f;   // 1/sqrt(192)

    // all-ones bf16 fragment for row-sum MFMA
    s16x8 onesf;
    #pragma unroll
    for (int j = 0; j < 8; ++j) onesf[j] = (short)0x3F80;

    // Q fragments in registers: subtile s rows row0 + s*64 + qw + l16
    s16x8 qf[2][6];
    #pragma unroll
    for (int s = 0; s < 2; ++s)
        #pragma unroll
        for (int kc = 0; kc < 6; ++kc)
            qf[s][kc] = *(const s16x8*)&qb[(size_t)(row0 + s * 64 + qw + l16) * 3072
                                           + h * 192 + kc * 32 + quad * 8];

    float m = -__builtin_inff();
    f32x4 l[2] = {(f32x4){0.f,0.f,0.f,0.f}, (f32x4){0.f,0.f,0.f,0.f}};
    f32x4 O[2][8];
    #pragma unroll
    for (int s = 0; s < 2; ++s)
        #pragma unroll
        for (int vi = 0; vi < 8; ++vi) O[s][vi] = (f32x4){0.f,0.f,0.f,0.f};

    const u16* vtb = vt + ((size_t)(b * 16 + h) * 128) * 2048;

    for (int kt = 0; kt < 32; ++kt) {
        const int krow0 = b * 2048 + kt * 64;
        __syncthreads();   // prior iteration's Ks/Vs/Ps reads complete
        // stage K tile (64 x 192): nope from kvup, rope from krot
        #pragma unroll
        for (int i = 0; i < 6; ++i) {
            int idx = tid + i * 256;
            int r = idx / 24, c = (idx % 24) * 8;
            const u16* src = (c < 128)
                ? &kvup[(size_t)(krow0 + r) * 4096 + h * 256 + c]
                : &krot[(size_t)(krow0 + r) * 64 + (c - 128)];
            *(s16x8*)&Ks[r][c] = *(const s16x8*)src;
        }
        // stage V tile from vt: contiguous b128 rows
        #pragma unroll
        for (int i = 0; i < 4; ++i) {
            int idx = tid + i * 256;
            int r = idx >> 3, c8 = (idx & 7) * 8;
            *(s16x8*)&Vs[r][c8] = *(const s16x8*)&vtb[(size_t)r * 2048 + kt * 64 + c8];
        }
        __syncthreads();

        // ---- QK^T: both subtiles share Ks fragments ----
        f32x4 S[2][4];
        #pragma unroll
        for (int s = 0; s < 2; ++s)
            #pragma unroll
            for (int ct = 0; ct < 4; ++ct) S[s][ct] = (f32x4){0.f,0.f,0.f,0.f};
        #pragma unroll
        for (int kc = 0; kc < 6; ++kc) {
            #pragma unroll
            for (int ct = 0; ct < 4; ++ct) {
                s16x8 bf = *(const s16x8*)&Ks[ct * 16 + l16][kc * 32 + quad * 8];
                S[0][ct] = __builtin_amdgcn_mfma_f32_16x16x32_bf16(qf[0][kc], bf, S[0][ct], 0, 0, 0);
                S[1][ct] = __builtin_amdgcn_mfma_f32_16x16x32_bf16(qf[1][kc], bf, S[1][ct], 0, 0, 0);
            }
        }
        // scale + mask
        #pragma unroll
        for (int ct = 0; ct < 4; ++ct) {
            float mv = mask[b * 2048 + kt * 64 + ct * 16 + l16];
            #pragma unroll
            for (int s = 0; s < 2; ++s)
                #pragma unroll
                for (int r = 0; r < 4; ++r) S[s][ct][r] = S[s][ct][r] * scale + mv;
        }
        // wave-shared max (upper bound over all 32 rows x 64 cols of this wave)
        float tm = S[0][0][0];
        #pragma unroll
        for (int s = 0; s < 2; ++s)
            #pragma unroll
            for (int ct = 0; ct < 4; ++ct)
                #pragma unroll
                for (int r = 0; r < 4; ++r) tm = fmaxf(tm, S[s][ct][r]);
        #pragma unroll
        for (int off = 1; off < 64; off <<= 1)
            tm = fmaxf(tm, __shfl_xor(tm, off, 64));
        float mn = fmaxf(m, tm);
        float alpha = __expf(m - mn);
        m = mn;
        // P = exp(S - m) -> bf16 -> Ps (wave-private rows; same-wave RAW)
        #pragma unroll
        for (int s = 0; s < 2; ++s)
            #pragma unroll
            for (int ct = 0; ct < 4; ++ct)
                #pragma unroll
                for (int r = 0; r < 4; ++r)
                    Ps[s * 64 + qw + quad * 4 + r][ct * 16 + l16] = f2bf(__expf(S[s][ct][r] - m));
        // rescale O and l by alpha (wave-uniform)
        #pragma unroll
        for (int s = 0; s < 2; ++s) {
            l[s] *= alpha;
            #pragma unroll
            for (int vi = 0; vi < 8; ++vi) O[s][vi] *= alpha;
        }
        // ---- PV + row-sum via ones-MFMA; Vs fragments shared across subtiles ----
        #pragma unroll
        for (int kc = 0; kc < 2; ++kc) {
            s16x8 a0 = *(const s16x8*)&Ps[qw + l16][kc * 32 + quad * 8];
            s16x8 a1 = *(const s16x8*)&Ps[64 + qw + l16][kc * 32 + quad * 8];
            #pragma unroll
            for (int vi = 0; vi < 8; ++vi) {
                s16x8 bf = *(const s16x8*)&Vs[vi * 16 + l16][kc * 32 + quad * 8];
                O[0][vi] = __builtin_amdgcn_mfma_f32_16x16x32_bf16(a0, bf, O[0][vi], 0, 0, 0);
                O[1][vi] = __builtin_amdgcn_mfma_f32_16x16x32_bf16(a1, bf, O[1][vi], 0, 0, 0);
            }
            l[0] = __builtin_amdgcn_mfma_f32_16x16x32_bf16(a0, onesf, l[0], 0, 0, 0);
            l[1] = __builtin_amdgcn_mfma_f32_16x16x32_bf16(a1, onesf, l[1], 0, 0, 0);
        }
    }

    // epilogue: normalize and store
    #pragma unroll
    for (int s = 0; s < 2; ++s) {
        f32x4 linv;
        #pragma unroll
        for (int r = 0; r < 4; ++r) linv[r] = 1.0f / l[s][r];
        #pragma unroll
        for (int vi = 0; vi < 8; ++vi) {
            #pragma unroll
            for (int r = 0; r < 4; ++r) {
                int q_ = row0 + s * 64 + qw + quad * 4 + r;
                attnb[(size_t)q_ * 2048 + h * 128 + vi * 16 + l16] = f2bf(O[s][vi][r] * linv[r]);
            }
        }
    }
}

// ---------------------------------------------------------------------------
// Workspace layout (u16 elements): round-3 layout + vt at the end (122.7 MB).
// ---------------------------------------------------------------------------
extern "C" void kernel_launch(void* const* d_in, const int* in_sizes, int n_in,
                              void* d_out, int out_size, void* d_ws, size_t ws_size,
                              hipStream_t stream)
{
    const float* hidden = (const float*)d_in[0];
    const float* mask   = (const float*)d_in[1];
    const float* cosb   = (const float*)d_in[2];
    const float* sinb   = (const float*)d_in[3];
    const float* w_qd   = (const float*)d_in[4];
    const float* w_qu   = (const float*)d_in[5];
    const float* w_kvd  = (const float*)d_in[6];
    const float* w_kvu  = (const float*)d_in[7];
    const float* w_o    = (const float*)d_in[8];
    const float* qnw    = (const float*)d_in[9];
    const float* kvnw   = (const float*)d_in[10];
    float* out = (float*)d_out;

    u16* ws = (u16*)d_ws;
    u16* qbuf   = ws + 0;
    u16* wt_qd  = ws + 0;                       // dead before qbuf written
    u16* kvup   = ws + 12582912;
    u16* hid_bf = ws + 12582912;                // dead before kvup written
    u16* wt_kvd = ws + 20971520;                // dead before kvup written
    u16* attnb  = ws + 29360128;
    u16* qd     = ws + 29360128;                // dead before attnb written
    u16* wt_qu  = ws + 33554432;                // dead before attnb written
    u16* kvb    = ws + 37748736;
    u16* wt_o   = ws + 37748736;                // written after kvb dead (rope)
    u16* kvn    = ws + 40108032;
    u16* wt_kvu = ws + 42205184;
    u16* krot   = ws + 44302336;
    u16* vt     = ws + 44564480;                // 16,777,216 elems; end 122.7 MB

    // hidden f32 -> bf16
    {
        long long n2 = (long long)4096 * 2048 / 2;
        cvt_f32_bf16<<<(int)((n2 + 255) / 256), 256, 0, stream>>>(hidden, hid_bf, n2);
    }

    // q path
    transpose_f32_bf16<<<dim3(32, 64), 256, 0, stream>>>(w_qd, wt_qd, 2048, 1024);
    gemm128<u16><<<dim3(8, 32), 256, 0, stream>>>(hid_bf, wt_qd, qd, 4096, 1024, 2048);
    rmsnorm_kernel<<<4096, 256, 0, stream>>>(qd, qnw, qd, 1024, 1024, 1024);
    transpose_f32_bf16<<<dim3(96, 32), 256, 0, stream>>>(w_qu, wt_qu, 1024, 3072);
    gemm128<u16><<<dim3(24, 32), 256, 0, stream>>>(qd, wt_qu, qbuf, 4096, 3072, 1024);

    // kv path
    transpose_f32_bf16<<<dim3(18, 64), 256, 0, stream>>>(w_kvd, wt_kvd, 2048, 576);
    gemm_bf16<<<dim3(9, 64), 256, 0, stream>>>(hid_bf, wt_kvd, kvb, 4096, 576, 2048);
    rmsnorm_kernel<<<4096, 256, 0, stream>>>(kvb, kvnw, kvn, 512, 576, 512);
    transpose_f32_bf16<<<dim3(128, 16), 256, 0, stream>>>(w_kvu, wt_kvu, 512, 4096);
    gemm128<u16><<<dim3(32, 32), 256, 0, stream>>>(kvn, wt_kvu, kvup, 4096, 4096, 512);

    // V transpose for attention staging
    transpose_v<<<dim3(64, 4, 32), 256, 0, stream>>>(kvup, vt);

    // rope (q in-place + krot); then wt_o into space freed by kvb/kvn
    rope_kernel<<<4096, 256, 0, stream>>>(qbuf, kvb, krot, cosb, sinb);
    transpose_f32_bf16<<<dim3(64, 64), 256, 0, stream>>>(w_o, wt_o, 2048, 2048);

    // attention (MFMA flash v3)
    attn_mfma3<<<dim3(16, 16, 2), 256, 0, stream>>>(qbuf, kvup, krot, vt, mask, attnb);

    // output projection -> FLOAT32 output
    gemm128<float><<<dim3(16, 32), 256, 0, stream>>>(attnb, wt_o, out, 4096, 2048, 2048);
}